// Round 8
// baseline (733.792 us; speedup 1.0000x reference)
//
#include <hip/hip_runtime.h>
#include <hip/hip_fp16.h>
#include <math.h>

#define CUTOFF_INV 0.2f
#define EPB_SHIFT 11
#define EPB 2048
#define NBIN_MAX 512
#define P1_CHUNK 4096
#define P1_THREADS 512
#define GC_STRIDE 16   // gcount padding: 64B per counter

typedef unsigned int uint;
typedef unsigned short ushort;

__device__ __forceinline__ float fcut(float r) {
    // 1 - 6p^5 + 15p^4 - 10p^3, p = r/cutoff
    float p = r * CUTOFF_INV;
    float p2 = p * p;
    float p3 = p2 * p;
    return 1.0f + p3 * (-10.0f + p * (15.0f - 6.0f * p));
}

// spherical-plus-norm legendre factors: s_l = sqrt((2l+1)/pi) * P_l(ca)
__device__ __forceinline__ void legendre_s(float ca, float& s0, float& s1, float& s2) {
    s0 = 0.5641895835477563f;
    s1 = 0.9772050238058398f * ca;
    s2 = 1.2615662610100802f * (1.5f * ca * ca - 0.5f);
}

// radial part: v[l*3+n] = j_l(z_{l,n} * rik / cutoff) * fc(rik). Pure VALU (~free).
__device__ __forceinline__ void radial9(float rik, float* v) {
    float rr = rik * CUTOFF_INV;
    float fcik = fcut(rik);
    {   // l = 0: j0 = sin(x)/x
        const float Z0[3] = {3.14159265358979324f, 6.28318530717958648f, 9.42477796076937972f};
#pragma unroll
        for (int n = 0; n < 3; ++n) {
            float x = Z0[n] * rr;
            v[n] = (__sinf(x) / x) * fcik;
        }
    }
    {   // l = 1: j1 = (sin/x - cos)/x
        const float Z1[3] = {4.49340945790806150f, 7.72525183693865170f, 10.9041216594298970f};
#pragma unroll
        for (int n = 0; n < 3; ++n) {
            float x = Z1[n] * rr;
            float s, c;
            __sincosf(x, &s, &c);
            float invx = 1.0f / x;
            v[3 + n] = ((s * invx - c) * invx) * fcik;
        }
    }
    {   // l = 2: j2 = 3/x*j1 - j0
        const float Z2[3] = {5.76345919689554900f, 9.09501133047736000f, 12.3229409705673230f};
#pragma unroll
        for (int n = 0; n < 3; ++n) {
            float x = Z2[n] * rr;
            float s, c;
            __sincosf(x, &s, &c);
            float invx = 1.0f / x;
            float sx = s * invx;
            float j1 = (sx - c) * invx;
            v[6 + n] = (3.0f * invx * j1 - sx) * fcik;
        }
    }
}

// ---------------- Stage 1: node gate = sigmoid(nf @ W1 + b1) -> [N,stride] ----------------
__global__ void node_gate_kernel(const float* __restrict__ nf,
                                 const float* __restrict__ W1,
                                 const float* __restrict__ b1,
                                 float* __restrict__ gate, int N, int stride) {
    __shared__ float sW[64 * 9];
    __shared__ float sb[9];
    for (int i = threadIdx.x; i < 576; i += blockDim.x) sW[i] = W1[i];
    if (threadIdx.x < 9) sb[threadIdx.x] = b1[threadIdx.x];
    __syncthreads();
    int t = blockIdx.x * blockDim.x + threadIdx.x;
    if (t >= N) return;
    float acc[9];
#pragma unroll
    for (int d = 0; d < 9; ++d) acc[d] = sb[d];
    const float* row = nf + (size_t)t * 64;
#pragma unroll
    for (int f = 0; f < 64; ++f) {
        float x = row[f];
#pragma unroll
        for (int d = 0; d < 9; ++d) acc[d] += x * sW[f * 9 + d];
    }
    float* g = gate + (size_t)t * stride;
#pragma unroll
    for (int d = 0; d < 9; ++d) g[d] = 1.0f / (1.0f + __expf(-acc[d]));
    for (int d = 9; d < stride; ++d) g[d] = 0.0f;
}

// ---------------- Stage 2a: per-edge packed table tab[e] = (f16(rik) << 16) | nk ----------------
__global__ void edge_tab_kernel(const float* __restrict__ dist,
                                const int* __restrict__ eidx,   // [2,E]
                                uint* __restrict__ tab, int E) {
    int e = blockIdx.x * blockDim.x + threadIdx.x;
    if (e >= E) return;
    uint rh = (uint)__half_as_ushort(__float2half_rn(dist[e]));
    tab[e] = (rh << 16) | (uint)eidx[E + e];
}

// overflow fallback: accumulate one record straight into global mid
__device__ __forceinline__ void spill_rec(uint2 rec, int bin,
                                          const float* __restrict__ gate16,
                                          float* __restrict__ mid) {
    float ca  = __half2float(__ushort_as_half((ushort)(rec.x >> 16)));
    float rik = __half2float(__ushort_as_half((ushort)(rec.x & 0xFFFFu)));
    uint nk  = rec.y & 0xFFFFu;
    uint ijl = rec.y >> 16;
    float vr[9];
    radial9(rik, vr);
    float s0, s1, s2;
    legendre_s(ca, s0, s1, s2);
    const float* g = gate16 + ((size_t)nk << 4);
    float* dst = mid + ((size_t)bin * EPB + ijl) * 9;
    atomicAdd(dst + 0, vr[0] * g[0] * s0);
    atomicAdd(dst + 1, vr[1] * g[1] * s0);
    atomicAdd(dst + 2, vr[2] * g[2] * s0);
    atomicAdd(dst + 3, vr[3] * g[3] * s1);
    atomicAdd(dst + 4, vr[4] * g[4] * s1);
    atomicAdd(dst + 5, vr[5] * g[5] * s1);
    atomicAdd(dst + 6, vr[6] * g[6] * s2);
    atomicAdd(dst + 7, vr[7] * g[7] * s2);
    atomicAdd(dst + 8, vr[8] * g[8] * s2);
}

// ---------------- Pass 1: block-local counting sort -> binned self-contained records ----------------
// record = {ca_f16<<16 | rik_f16, ijl<<16 | nk}. One 4B gather from the 4MB tab per triplet.
__global__ void __launch_bounds__(P1_THREADS) p1_sort_kernel(
        const float* __restrict__ ang,
        const int* __restrict__ tidx, // [2,T]
        const uint* __restrict__ tab, // [E]
        uint* __restrict__ gcount,    // [NBIN*GC_STRIDE]
        uint2* __restrict__ binbuf,   // [NBIN*BCAP]
        const float* __restrict__ gate16,
        float* __restrict__ mid,
        int T, int NBIN, int BCAP) {
    __shared__ uint hist[NBIN_MAX];
    __shared__ uint sc[NBIN_MAX];     // inclusive scan -> exclusive prefix
    __shared__ uint gbase[NBIN_MAX];
    __shared__ uint lcur[NBIN_MAX];
    __shared__ uint2 sbuf[P1_CHUNK];
    __shared__ ushort sbin[P1_CHUNK];

    int t0 = blockIdx.x * P1_CHUNK;
    int m = T - t0;
    if (m <= 0) return;
    if (m > P1_CHUNK) m = P1_CHUNK;
    int tid = threadIdx.x;

    for (int i = tid; i < NBIN; i += blockDim.x) { hist[i] = 0; lcur[i] = 0; }
    __syncthreads();

    // pass A: histogram (reads tidx row 0 only)
    for (int i = tid; i < m; i += blockDim.x)
        atomicAdd(&hist[((uint)tidx[t0 + i]) >> EPB_SHIFT], 1u);
    __syncthreads();

    // inclusive scan of hist into sc (NBIN <= blockDim)
    if (tid < NBIN) sc[tid] = hist[tid];
    __syncthreads();
    for (int off = 1; off < NBIN; off <<= 1) {
        uint v = 0;
        if (tid < NBIN) {
            v = sc[tid];
            if (tid >= off) v += sc[tid - off];
        }
        __syncthreads();
        if (tid < NBIN) sc[tid] = v;
        __syncthreads();
    }
    // exclusive prefix + global reservation
    uint ex = 0, h = 0;
    if (tid < NBIN) {
        h = hist[tid];
        ex = sc[tid] - h;
    }
    __syncthreads();
    if (tid < NBIN) {
        sc[tid] = ex;
        gbase[tid] = h ? atomicAdd(&gcount[tid * GC_STRIDE], h) : 0u;
    }
    __syncthreads();

    // pass B: build records (tab gather: 4B from L2-resident 4MB), place sorted by bin
    for (int i = tid; i < m; i += blockDim.x) {
        int t = t0 + i;
        uint ij = (uint)tidx[t];
        uint ik = (uint)tidx[T + t];
        float ca = ang[t];
        uint te = tab[ik];   // (rik_f16 << 16) | nk
        uint bin = ij >> EPB_SHIFT;
        uint loc = atomicAdd(&lcur[bin], 1u);
        uint p = sc[bin] + loc;
        uint cah = (uint)__half_as_ushort(__float2half_rn(ca));
        sbuf[p] = make_uint2((cah << 16) | (te >> 16),
                             ((ij & (EPB - 1u)) << 16) | (te & 0xFFFFu));
        sbin[p] = (ushort)bin;
    }
    __syncthreads();

    // pass C: coalesced writeout of sorted runs
    for (int i = tid; i < m; i += blockDim.x) {
        uint bin = sbin[i];
        uint2 rec = sbuf[i];
        uint slot = gbase[bin] + ((uint)i - sc[bin]);
        if (slot < (uint)BCAP)
            binbuf[(size_t)bin * BCAP + slot] = rec;
        else
            spill_rec(rec, bin, gate16, mid);
    }
}

// ---------------- Pass 2 (fused): per-bin accumulate in LDS, merge, GatedMLP epilogue ----------------
// Per record: gate16[nk] gather (36B from 3.2MB, L2-hot) + inline radial/legendre compute
// + 9 LDS atomics. No more 64MB A-table -> no L2-miss MSHR wall.
__global__ void __launch_bounds__(1024) p2_fused_kernel(const float* __restrict__ dist,
                                                        const float* __restrict__ gate16, // [N,16]
                                                        const uint* __restrict__ gcount,  // [NBIN*GC_STRIDE]
                                                        const uint2* __restrict__ binbuf,
                                                        const float* __restrict__ mid,    // [E,9] spill acc
                                                        const float* __restrict__ attr,
                                                        const float* __restrict__ Wm,
                                                        const float* __restrict__ bm,
                                                        const float* __restrict__ Wg,
                                                        const float* __restrict__ bg,
                                                        float* __restrict__ out,
                                                        int E, int BCAP) {
    __shared__ float lmid[EPB * 9];   // 72 KB
    __shared__ float sWm[576], sWg[576], sbm[64], sbg[64];
    for (int i = threadIdx.x; i < 576; i += blockDim.x) {
        sWm[i] = Wm[i];
        sWg[i] = Wg[i];
    }
    if (threadIdx.x < 64) {
        sbm[threadIdx.x] = bm[threadIdx.x];
        sbg[threadIdx.x] = bg[threadIdx.x];
    }
    int b = blockIdx.x;
    int ebase = b << EPB_SHIFT;
    int ecnt = min(EPB, E - ebase);
    for (int i = threadIdx.x; i < EPB * 9; i += blockDim.x) lmid[i] = 0.0f;
    __syncthreads();

    uint n = gcount[b * GC_STRIDE];
    if (n > (uint)BCAP) n = (uint)BCAP;
    const uint2* rb = binbuf + (size_t)b * BCAP;
    uint bd = blockDim.x;
    uint i = threadIdx.x;

#define ACC_ONE(rr_, g0_, g1_, g8_)                                   \
    {                                                                 \
        float ca  = __half2float(__ushort_as_half((ushort)(rr_.x >> 16)));     \
        float rik = __half2float(__ushort_as_half((ushort)(rr_.x & 0xFFFFu))); \
        uint ijl = rr_.y >> 16;                                       \
        float vr[9];                                                  \
        radial9(rik, vr);                                             \
        float s0, s1, s2;                                             \
        legendre_s(ca, s0, s1, s2);                                   \
        float* d = &lmid[ijl * 9];                                    \
        atomicAdd(d + 0, vr[0] * g0_.x * s0);                         \
        atomicAdd(d + 1, vr[1] * g0_.y * s0);                         \
        atomicAdd(d + 2, vr[2] * g0_.z * s0);                         \
        atomicAdd(d + 3, vr[3] * g0_.w * s1);                         \
        atomicAdd(d + 4, vr[4] * g1_.x * s1);                         \
        atomicAdd(d + 5, vr[5] * g1_.y * s1);                         \
        atomicAdd(d + 6, vr[6] * g1_.z * s2);                         \
        atomicAdd(d + 7, vr[7] * g1_.w * s2);                         \
        atomicAdd(d + 8, vr[8] * g8_ * s2);                           \
    }

    for (; i + 3 * bd < n; i += 4 * bd) {
        uint2 r0 = rb[i];
        uint2 r1 = rb[i + bd];
        uint2 r2 = rb[i + 2 * bd];
        uint2 r3 = rb[i + 3 * bd];
        const float4* G0 = (const float4*)(gate16 + ((size_t)(r0.y & 0xFFFFu) << 4));
        const float4* G1 = (const float4*)(gate16 + ((size_t)(r1.y & 0xFFFFu) << 4));
        const float4* G2 = (const float4*)(gate16 + ((size_t)(r2.y & 0xFFFFu) << 4));
        const float4* G3 = (const float4*)(gate16 + ((size_t)(r3.y & 0xFFFFu) << 4));
        float4 g00 = G0[0], g01 = G0[1]; float g08 = *((const float*)(G0 + 2));
        float4 g10 = G1[0], g11 = G1[1]; float g18 = *((const float*)(G1 + 2));
        float4 g20 = G2[0], g21 = G2[1]; float g28 = *((const float*)(G2 + 2));
        float4 g30 = G3[0], g31 = G3[1]; float g38 = *((const float*)(G3 + 2));
        ACC_ONE(r0, g00, g01, g08)
        ACC_ONE(r1, g10, g11, g18)
        ACC_ONE(r2, g20, g21, g28)
        ACC_ONE(r3, g30, g31, g38)
    }
    for (; i < n; i += bd) {
        uint2 rr = rb[i];
        const float4* G = (const float4*)(gate16 + ((size_t)(rr.y & 0xFFFFu) << 4));
        float4 q0 = G[0], q1 = G[1];
        float q8 = *((const float*)(G + 2));
        ACC_ONE(rr, q0, q1, q8)
    }
#undef ACC_ONE

    __syncthreads();
    // merge pass: fold fc(rij) and spill-mid into lmid with coalesced loads
    for (int el = threadIdx.x; el < ecnt; el += blockDim.x) {
        int e = ebase + el;
        float fc = fcut(dist[e]);
        const float* mg = mid + (size_t)e * 9;
        float* ls = &lmid[el * 9];
#pragma unroll
        for (int d = 0; d < 9; ++d) ls[d] = fc * (ls[d] + mg[d]);
    }
    __syncthreads();

    // GatedMLP epilogue: wave per edge, lane = feature; LDS + streamed attr/out only.
    int wid  = threadIdx.x >> 6;
    int lane = threadIdx.x & 63;
    int nw   = blockDim.x >> 6;
    for (int el = wid; el < ecnt; el += nw) {
        int e = ebase + el;
        const float* ls = &lmid[el * 9];
        float am = sbm[lane], ag = sbg[lane];
#pragma unroll
        for (int d = 0; d < 9; ++d) {
            float ud = ls[d];
            am += ud * sWm[d * 64 + lane];
            ag += ud * sWg[d * 64 + lane];
        }
        float h  = am / (1.0f + __expf(-am));   // silu
        float gt = 1.0f / (1.0f + __expf(-ag)); // sigmoid
        size_t off = (size_t)e * 64 + lane;
        out[off] = attr[off] + h * gt;
    }
}

// ---------------- Legacy fallback triplet kernel (round-1 path) ----------------
__global__ void triplet_kernel(const float* __restrict__ dist,
                               const float* __restrict__ ang,
                               const int* __restrict__ tidx,
                               const int* __restrict__ eidx,
                               const float* __restrict__ gate,
                               float* __restrict__ mid,
                               int T, int E) {
    int t = blockIdx.x * blockDim.x + threadIdx.x;
    if (t >= T) return;
    int ij = tidx[t];
    int ik = tidx[T + t];
    float ca  = ang[t];
    float rij = dist[ij];
    float rik = dist[ik];
    float fc = fcut(rij) * fcut(rik);
    float s0, s1, s2;
    legendre_s(ca, s0, s1, s2);
    s0 *= fc; s1 *= fc; s2 *= fc;
    int nk = eidx[E + ik];
    const float* g = gate + (size_t)nk * 9;
    float vr[9];
    radial9(rik, vr);
    // note: radial9 includes fc(rik); the fc above already has fc(rik) -> divide out
    // (legacy path kept simple: recompute without double-count)
    float fcik = fcut(rik);
    float inv = fcik > 1e-20f ? 1.0f / fcik : 0.0f;
    float* dst = mid + (size_t)ij * 9;
    float w0 = s0 * fcut(rij) * fcut(rik) * inv;  // == s0*fc(rij), applied to vr (has fcik)
    // simpler: vr already has fcik; multiply by s_l * fc(rij)
    float frij = fcut(rij);
    atomicAdd(dst + 0, vr[0] * (0.5641895835477563f) * frij * g[0]);
    atomicAdd(dst + 1, vr[1] * (0.5641895835477563f) * frij * g[1]);
    atomicAdd(dst + 2, vr[2] * (0.5641895835477563f) * frij * g[2]);
    float l1 = 0.9772050238058398f * ca * frij;
    atomicAdd(dst + 3, vr[3] * l1 * g[3]);
    atomicAdd(dst + 4, vr[4] * l1 * g[4]);
    atomicAdd(dst + 5, vr[5] * l1 * g[5]);
    float l2 = 1.2615662610100802f * (1.5f * ca * ca - 0.5f) * frij;
    atomicAdd(dst + 6, vr[6] * l2 * g[6]);
    atomicAdd(dst + 7, vr[7] * l2 * g[7]);
    atomicAdd(dst + 8, vr[8] * l2 * g[8]);
    (void)w0; (void)inv; (void)fc; (void)s1; (void)s2; (void)s0;
}

// ---------------- Legacy Stage 3 (fallback path only) ----------------
__global__ void edge_kernel(const float* __restrict__ mid,
                            const float* __restrict__ attr,
                            const float* __restrict__ Wm, const float* __restrict__ bm,
                            const float* __restrict__ Wg, const float* __restrict__ bg,
                            float* __restrict__ out, int E) {
    __shared__ float sWm[9 * 64], sWg[9 * 64], sbm[64], sbg[64];
    for (int i = threadIdx.x; i < 576; i += blockDim.x) {
        sWm[i] = Wm[i];
        sWg[i] = Wg[i];
    }
    if (threadIdx.x < 64) {
        sbm[threadIdx.x] = bm[threadIdx.x];
        sbg[threadIdx.x] = bg[threadIdx.x];
    }
    __syncthreads();
    int wid  = threadIdx.x >> 6;
    int lane = threadIdx.x & 63;
    int e = blockIdx.x * (blockDim.x >> 6) + wid;
    if (e >= E) return;
    const float* u = mid + (size_t)e * 9;
    float am = sbm[lane], ag = sbg[lane];
#pragma unroll
    for (int d = 0; d < 9; ++d) {
        float ud = u[d];
        am += ud * sWm[d * 64 + lane];
        ag += ud * sWg[d * 64 + lane];
    }
    float h  = am / (1.0f + __expf(-am));
    float gt = 1.0f / (1.0f + __expf(-ag));
    size_t off = (size_t)e * 64 + lane;
    out[off] = attr[off] + h * gt;
}

extern "C" void kernel_launch(void* const* d_in, const int* in_sizes, int n_in,
                              void* d_out, int out_size, void* d_ws, size_t ws_size,
                              hipStream_t stream) {
    const float* dist = (const float*)d_in[0];
    const float* ang  = (const float*)d_in[1];
    const float* nf   = (const float*)d_in[2];
    const float* attr = (const float*)d_in[3];
    const float* W1   = (const float*)d_in[4];
    const float* b1   = (const float*)d_in[5];
    const float* Wm   = (const float*)d_in[6];
    const float* bm   = (const float*)d_in[7];
    const float* Wg   = (const float*)d_in[8];
    const float* bg   = (const float*)d_in[9];
    const int* tidx   = (const int*)d_in[10];
    const int* eidx   = (const int*)d_in[11];

    int E = in_sizes[0];
    int T = in_sizes[1];
    int N = in_sizes[2] / 64;

    int NBIN = (E + EPB - 1) >> EPB_SHIFT;
    int mean = T / (NBIN > 0 ? NBIN : 1);
    int BCAP = ((mean + mean / 8 + 512) + 15) & ~15;   // ~20 sigma headroom, 16-aligned

    // ws layout (floats): gate16[N*16] | tab[E] | mid[E*9] | gcount[NBIN*16] | binbuf[NBIN*BCAP*2]
    size_t o_gate  = 0;
    size_t o_tab   = o_gate + (size_t)N * 16;
    size_t o_mid   = o_tab + (size_t)E;
    size_t o_gcnt  = o_mid + (size_t)E * 9;
    size_t o_bb    = (o_gcnt + (size_t)NBIN * GC_STRIDE + 15) & ~(size_t)15;  // 64B-align binbuf
    size_t total   = o_bb + (size_t)NBIN * BCAP * 2;

    bool newpath = (E <= (1 << 20)) && (N <= 65535) && (NBIN <= NBIN_MAX)
                   && (NBIN <= P1_THREADS) && (ws_size >= total * 4);

    float* wsf = (float*)d_ws;

    if (newpath) {
        float* gate16 = wsf + o_gate;
        uint*  tab    = (uint*)(wsf + o_tab);
        float* mid    = wsf + o_mid;
        uint*  gcount = (uint*)(wsf + o_gcnt);
        uint2* binbuf = (uint2*)(wsf + o_bb);

        hipMemsetAsync(gcount, 0, (size_t)NBIN * GC_STRIDE * sizeof(uint), stream);
        hipMemsetAsync(mid, 0, (size_t)E * 9 * sizeof(float), stream);
        node_gate_kernel<<<(N + 255) / 256, 256, 0, stream>>>(nf, W1, b1, gate16, N, 16);
        edge_tab_kernel<<<(E + 255) / 256, 256, 0, stream>>>(dist, eidx, tab, E);

        int p1grid = (T + P1_CHUNK - 1) / P1_CHUNK;
        p1_sort_kernel<<<p1grid, P1_THREADS, 0, stream>>>(ang, tidx, tab, gcount, binbuf,
                                                          gate16, mid, T, NBIN, BCAP);
        p2_fused_kernel<<<NBIN, 1024, 0, stream>>>(dist, gate16, gcount, binbuf, mid,
                                                   attr, Wm, bm, Wg, bg,
                                                   (float*)d_out, E, BCAP);
    } else {
        // legacy path (round-1)
        float* gate = wsf;
        float* mid = gate + (((size_t)N * 9 + 15) & ~(size_t)15);
        hipMemsetAsync(mid, 0, (size_t)E * 9 * sizeof(float), stream);
        node_gate_kernel<<<(N + 255) / 256, 256, 0, stream>>>(nf, W1, b1, gate, N, 9);
        triplet_kernel<<<(T + 255) / 256, 256, 0, stream>>>(dist, ang, tidx, eidx, gate, mid, T, E);
        edge_kernel<<<(E + 3) / 4, 256, 0, stream>>>(mid, attr, Wm, bm, Wg, bg, (float*)d_out, E);
    }
}

// Round 9
// 726.285 us; speedup vs baseline: 1.0103x; 1.0103x over previous
//
#include <hip/hip_runtime.h>
#include <hip/hip_fp16.h>
#include <math.h>

#define CUTOFF_INV 0.2f
#define EPB_SHIFT 11
#define EPB 2048
#define NBIN_MAX 512
#define P1_CHUNK 4096
#define P1_THREADS 512
#define GC_STRIDE 16   // gcount padding: 64B per counter

typedef unsigned int uint;
typedef unsigned short ushort;

__device__ __forceinline__ float fcut(float r) {
    // 1 - 6p^5 + 15p^4 - 10p^3, p = r/cutoff
    float p = r * CUTOFF_INV;
    float p2 = p * p;
    float p3 = p2 * p;
    return 1.0f + p3 * (-10.0f + p * (15.0f - 6.0f * p));
}

// spherical-plus-norm legendre factors: s_l = sqrt((2l+1)/pi) * P_l(ca)
__device__ __forceinline__ void legendre_s(float ca, float& s0, float& s1, float& s2) {
    s0 = 0.5641895835477563f;
    s1 = 0.9772050238058398f * ca;
    s2 = 1.2615662610100802f * (1.5f * ca * ca - 0.5f);
}

// radial part, divide-free: one v_rcp + NR, all 1/x via inv * (1/Z) const-folded.
// v[l*3+n] = j_l(z_{l,n} * rik / cutoff) * fc(rik)
__device__ __forceinline__ void radial9(float rik, float* v) {
    float rr = rik * CUTOFF_INV;           // (0, 1]
    float inv = __builtin_amdgcn_rcpf(rr);
    inv = inv * (2.0f - rr * inv);         // one NR refine
    float fcik = fcut(rik);

    const float Z0[3]  = {3.14159265358979324f, 6.28318530717958648f, 9.42477796076937972f};
    const float IZ0[3] = {1.0f / 3.14159265358979324f, 1.0f / 6.28318530717958648f, 1.0f / 9.42477796076937972f};
    const float Z1[3]  = {4.49340945790806150f, 7.72525183693865170f, 10.9041216594298970f};
    const float IZ1[3] = {1.0f / 4.49340945790806150f, 1.0f / 7.72525183693865170f, 1.0f / 10.9041216594298970f};
    const float Z2[3]  = {5.76345919689554900f, 9.09501133047736000f, 12.3229409705673230f};
    const float IZ2[3] = {1.0f / 5.76345919689554900f, 1.0f / 9.09501133047736000f, 1.0f / 12.3229409705673230f};

#pragma unroll
    for (int n = 0; n < 3; ++n) {          // l = 0: j0 = sin(x) * invx
        float x = Z0[n] * rr;
        float invx = IZ0[n] * inv;
        v[n] = __sinf(x) * invx * fcik;
    }
#pragma unroll
    for (int n = 0; n < 3; ++n) {          // l = 1: j1 = (sin*invx - cos)*invx
        float x = Z1[n] * rr;
        float invx = IZ1[n] * inv;
        float s, c;
        __sincosf(x, &s, &c);
        v[3 + n] = (s * invx - c) * invx * fcik;
    }
#pragma unroll
    for (int n = 0; n < 3; ++n) {          // l = 2: j2 = 3*invx*j1 - j0
        float x = Z2[n] * rr;
        float invx = IZ2[n] * inv;
        float s, c;
        __sincosf(x, &s, &c);
        float sx = s * invx;
        float j1 = (sx - c) * invx;
        v[6 + n] = (3.0f * invx * j1 - sx) * fcik;
    }
}

__device__ __forceinline__ float h2f(uint w) { return __half2float(__ushort_as_half((ushort)w)); }

// ---------------- Stage 1 (new path): node gate -> packed f16 rows [N][8 uints] (32B) ----------------
__global__ void node_gate_h16_kernel(const float* __restrict__ nf,
                                     const float* __restrict__ W1,
                                     const float* __restrict__ b1,
                                     uint* __restrict__ gate16h, int N) {
    __shared__ float sW[64 * 9];
    __shared__ float sb[9];
    for (int i = threadIdx.x; i < 576; i += blockDim.x) sW[i] = W1[i];
    if (threadIdx.x < 9) sb[threadIdx.x] = b1[threadIdx.x];
    __syncthreads();
    int t = blockIdx.x * blockDim.x + threadIdx.x;
    if (t >= N) return;
    float acc[9];
#pragma unroll
    for (int d = 0; d < 9; ++d) acc[d] = sb[d];
    const float* row = nf + (size_t)t * 64;
#pragma unroll
    for (int f = 0; f < 64; ++f) {
        float x = row[f];
#pragma unroll
        for (int d = 0; d < 9; ++d) acc[d] += x * sW[f * 9 + d];
    }
    float g[9];
#pragma unroll
    for (int d = 0; d < 9; ++d) g[d] = 1.0f / (1.0f + __expf(-acc[d]));
    uint* o = gate16h + ((size_t)t << 3);
#pragma unroll
    for (int d = 0; d < 4; ++d) {
        uint lo = (uint)__half_as_ushort(__float2half_rn(g[2 * d]));
        uint hi = (uint)__half_as_ushort(__float2half_rn(g[2 * d + 1]));
        o[d] = lo | (hi << 16);
    }
    o[4] = (uint)__half_as_ushort(__float2half_rn(g[8]));
    o[5] = 0u; o[6] = 0u; o[7] = 0u;
}

// ---------------- Stage 1 (legacy path): f32 gate [N,9] ----------------
__global__ void node_gate_f32_kernel(const float* __restrict__ nf,
                                     const float* __restrict__ W1,
                                     const float* __restrict__ b1,
                                     float* __restrict__ gate, int N) {
    __shared__ float sW[64 * 9];
    __shared__ float sb[9];
    for (int i = threadIdx.x; i < 576; i += blockDim.x) sW[i] = W1[i];
    if (threadIdx.x < 9) sb[threadIdx.x] = b1[threadIdx.x];
    __syncthreads();
    int t = blockIdx.x * blockDim.x + threadIdx.x;
    if (t >= N) return;
    float acc[9];
#pragma unroll
    for (int d = 0; d < 9; ++d) acc[d] = sb[d];
    const float* row = nf + (size_t)t * 64;
#pragma unroll
    for (int f = 0; f < 64; ++f) {
        float x = row[f];
#pragma unroll
        for (int d = 0; d < 9; ++d) acc[d] += x * sW[f * 9 + d];
    }
#pragma unroll
    for (int d = 0; d < 9; ++d)
        gate[(size_t)t * 9 + d] = 1.0f / (1.0f + __expf(-acc[d]));
}

// ---------------- Stage 2a: per-edge packed table tab[e] = (f16(rik) << 16) | nk ----------------
__global__ void edge_tab_kernel(const float* __restrict__ dist,
                                const int* __restrict__ eidx,   // [2,E]
                                uint* __restrict__ tab, int E) {
    int e = blockIdx.x * blockDim.x + threadIdx.x;
    if (e >= E) return;
    uint rh = (uint)__half_as_ushort(__float2half_rn(dist[e]));
    tab[e] = (rh << 16) | (uint)eidx[E + e];
}

// unpack gate row (9 f16) and produce g[9] floats
__device__ __forceinline__ void load_gate9(const uint* __restrict__ gate16h, uint nk, float* g) {
    const uint* gr = gate16h + ((size_t)nk << 3);
    uint4 q = *(const uint4*)gr;
    uint q8 = gr[4];
    g[0] = h2f(q.x & 0xFFFFu); g[1] = h2f(q.x >> 16);
    g[2] = h2f(q.y & 0xFFFFu); g[3] = h2f(q.y >> 16);
    g[4] = h2f(q.z & 0xFFFFu); g[5] = h2f(q.z >> 16);
    g[6] = h2f(q.w & 0xFFFFu); g[7] = h2f(q.w >> 16);
    g[8] = h2f(q8 & 0xFFFFu);
}

// overflow fallback: accumulate one record straight into global mid
__device__ __forceinline__ void spill_rec(uint2 rec, int bin,
                                          const uint* __restrict__ gate16h,
                                          float* __restrict__ mid) {
    float ca  = h2f(rec.x >> 16);
    float rik = h2f(rec.x & 0xFFFFu);
    uint nk  = rec.y & 0xFFFFu;
    uint ijl = rec.y >> 16;
    float vr[9], g[9];
    radial9(rik, vr);
    load_gate9(gate16h, nk, g);
    float s0, s1, s2;
    legendre_s(ca, s0, s1, s2);
    float* dst = mid + ((size_t)bin * EPB + ijl) * 9;
    atomicAdd(dst + 0, vr[0] * g[0] * s0);
    atomicAdd(dst + 1, vr[1] * g[1] * s0);
    atomicAdd(dst + 2, vr[2] * g[2] * s0);
    atomicAdd(dst + 3, vr[3] * g[3] * s1);
    atomicAdd(dst + 4, vr[4] * g[4] * s1);
    atomicAdd(dst + 5, vr[5] * g[5] * s1);
    atomicAdd(dst + 6, vr[6] * g[6] * s2);
    atomicAdd(dst + 7, vr[7] * g[7] * s2);
    atomicAdd(dst + 8, vr[8] * g[8] * s2);
}

// ---------------- Pass 1: block-local counting sort -> binned self-contained records ----------------
// record = {ca_f16<<16 | rik_f16, ijl<<16 | nk}. One 4B gather from the 4MB tab per triplet.
__global__ void __launch_bounds__(P1_THREADS) p1_sort_kernel(
        const float* __restrict__ ang,
        const int* __restrict__ tidx, // [2,T]
        const uint* __restrict__ tab, // [E]
        uint* __restrict__ gcount,    // [NBIN*GC_STRIDE]
        uint2* __restrict__ binbuf,   // [NBIN*BCAP]
        const uint* __restrict__ gate16h,
        float* __restrict__ mid,
        int T, int NBIN, int BCAP) {
    __shared__ uint hist[NBIN_MAX];
    __shared__ uint sc[NBIN_MAX];     // inclusive scan -> exclusive prefix
    __shared__ uint gbase[NBIN_MAX];
    __shared__ uint lcur[NBIN_MAX];
    __shared__ uint2 sbuf[P1_CHUNK];
    __shared__ ushort sbin[P1_CHUNK];

    int t0 = blockIdx.x * P1_CHUNK;
    int m = T - t0;
    if (m <= 0) return;
    if (m > P1_CHUNK) m = P1_CHUNK;
    int tid = threadIdx.x;

    for (int i = tid; i < NBIN; i += blockDim.x) { hist[i] = 0; lcur[i] = 0; }
    __syncthreads();

    // pass A: histogram (reads tidx row 0 only)
    for (int i = tid; i < m; i += blockDim.x)
        atomicAdd(&hist[((uint)tidx[t0 + i]) >> EPB_SHIFT], 1u);
    __syncthreads();

    // inclusive scan of hist into sc (NBIN <= blockDim)
    if (tid < NBIN) sc[tid] = hist[tid];
    __syncthreads();
    for (int off = 1; off < NBIN; off <<= 1) {
        uint v = 0;
        if (tid < NBIN) {
            v = sc[tid];
            if (tid >= off) v += sc[tid - off];
        }
        __syncthreads();
        if (tid < NBIN) sc[tid] = v;
        __syncthreads();
    }
    // exclusive prefix + global reservation
    uint ex = 0, h = 0;
    if (tid < NBIN) {
        h = hist[tid];
        ex = sc[tid] - h;
    }
    __syncthreads();
    if (tid < NBIN) {
        sc[tid] = ex;
        gbase[tid] = h ? atomicAdd(&gcount[tid * GC_STRIDE], h) : 0u;
    }
    __syncthreads();

    // pass B: build records (tab gather: 4B from L2-hot 4MB), place sorted by bin
    for (int i = tid; i < m; i += blockDim.x) {
        int t = t0 + i;
        uint ij = (uint)tidx[t];
        uint ik = (uint)tidx[T + t];
        float ca = ang[t];
        uint te = tab[ik];   // (rik_f16 << 16) | nk
        uint bin = ij >> EPB_SHIFT;
        uint loc = atomicAdd(&lcur[bin], 1u);
        uint p = sc[bin] + loc;
        uint cah = (uint)__half_as_ushort(__float2half_rn(ca));
        sbuf[p] = make_uint2((cah << 16) | (te >> 16),
                             ((ij & (EPB - 1u)) << 16) | (te & 0xFFFFu));
        sbin[p] = (ushort)bin;
    }
    __syncthreads();

    // pass C: coalesced writeout of sorted runs
    for (int i = tid; i < m; i += blockDim.x) {
        uint bin = sbin[i];
        uint2 rec = sbuf[i];
        uint slot = gbase[bin] + ((uint)i - sc[bin]);
        if (slot < (uint)BCAP)
            binbuf[(size_t)bin * BCAP + slot] = rec;
        else
            spill_rec(rec, bin, gate16h, mid);
    }
}

// ---------------- Pass 2 (fused): per-bin accumulate in LDS, merge, GatedMLP epilogue ----------------
// Per record: gate16h[nk] gather (20B from 1.6MB L2-hot table) + divide-free radial/legendre
// + 9 LDS atomics.
__global__ void __launch_bounds__(1024) p2_fused_kernel(const float* __restrict__ dist,
                                                        const uint* __restrict__ gate16h, // [N,8]
                                                        const uint* __restrict__ gcount,  // [NBIN*GC_STRIDE]
                                                        const uint2* __restrict__ binbuf,
                                                        const float* __restrict__ mid,    // [E,9] spill acc
                                                        const float* __restrict__ attr,
                                                        const float* __restrict__ Wm,
                                                        const float* __restrict__ bm,
                                                        const float* __restrict__ Wg,
                                                        const float* __restrict__ bg,
                                                        float* __restrict__ out,
                                                        int E, int BCAP) {
    __shared__ float lmid[EPB * 9];   // 72 KB
    __shared__ float sWm[576], sWg[576], sbm[64], sbg[64];
    for (int i = threadIdx.x; i < 576; i += blockDim.x) {
        sWm[i] = Wm[i];
        sWg[i] = Wg[i];
    }
    if (threadIdx.x < 64) {
        sbm[threadIdx.x] = bm[threadIdx.x];
        sbg[threadIdx.x] = bg[threadIdx.x];
    }
    int b = blockIdx.x;
    int ebase = b << EPB_SHIFT;
    int ecnt = min(EPB, E - ebase);
    for (int i = threadIdx.x; i < EPB * 9; i += blockDim.x) lmid[i] = 0.0f;
    __syncthreads();

    uint n = gcount[b * GC_STRIDE];
    if (n > (uint)BCAP) n = (uint)BCAP;
    const uint2* rb = binbuf + (size_t)b * BCAP;
    uint bd = blockDim.x;
    uint i = threadIdx.x;

#define ACC_ONE(rr_, q_, q8_)                                         \
    {                                                                 \
        float ca  = h2f(rr_.x >> 16);                                 \
        float rik = h2f(rr_.x & 0xFFFFu);                             \
        uint ijl = rr_.y >> 16;                                       \
        float vr[9];                                                  \
        radial9(rik, vr);                                             \
        float s0, s1, s2;                                             \
        legendre_s(ca, s0, s1, s2);                                   \
        float* d = &lmid[ijl * 9];                                    \
        atomicAdd(d + 0, vr[0] * h2f(q_.x & 0xFFFFu) * s0);           \
        atomicAdd(d + 1, vr[1] * h2f(q_.x >> 16) * s0);               \
        atomicAdd(d + 2, vr[2] * h2f(q_.y & 0xFFFFu) * s0);           \
        atomicAdd(d + 3, vr[3] * h2f(q_.y >> 16) * s1);               \
        atomicAdd(d + 4, vr[4] * h2f(q_.z & 0xFFFFu) * s1);           \
        atomicAdd(d + 5, vr[5] * h2f(q_.z >> 16) * s1);               \
        atomicAdd(d + 6, vr[6] * h2f(q_.w & 0xFFFFu) * s2);           \
        atomicAdd(d + 7, vr[7] * h2f(q_.w >> 16) * s2);               \
        atomicAdd(d + 8, vr[8] * h2f(q8_ & 0xFFFFu) * s2);            \
    }

    for (; i + 3 * bd < n; i += 4 * bd) {
        uint2 r0 = rb[i];
        uint2 r1 = rb[i + bd];
        uint2 r2 = rb[i + 2 * bd];
        uint2 r3 = rb[i + 3 * bd];
        const uint* G0 = gate16h + ((size_t)(r0.y & 0xFFFFu) << 3);
        const uint* G1 = gate16h + ((size_t)(r1.y & 0xFFFFu) << 3);
        const uint* G2 = gate16h + ((size_t)(r2.y & 0xFFFFu) << 3);
        const uint* G3 = gate16h + ((size_t)(r3.y & 0xFFFFu) << 3);
        uint4 q0 = *(const uint4*)G0; uint q08 = G0[4];
        uint4 q1 = *(const uint4*)G1; uint q18 = G1[4];
        uint4 q2 = *(const uint4*)G2; uint q28 = G2[4];
        uint4 q3 = *(const uint4*)G3; uint q38 = G3[4];
        ACC_ONE(r0, q0, q08)
        ACC_ONE(r1, q1, q18)
        ACC_ONE(r2, q2, q28)
        ACC_ONE(r3, q3, q38)
    }
    for (; i < n; i += bd) {
        uint2 rr = rb[i];
        const uint* G = gate16h + ((size_t)(rr.y & 0xFFFFu) << 3);
        uint4 q = *(const uint4*)G; uint q8 = G[4];
        ACC_ONE(rr, q, q8)
    }
#undef ACC_ONE

    __syncthreads();
    // merge pass: fold fc(rij) and spill-mid into lmid with coalesced loads
    for (int el = threadIdx.x; el < ecnt; el += blockDim.x) {
        int e = ebase + el;
        float fc = fcut(dist[e]);
        const float* mg = mid + (size_t)e * 9;
        float* ls = &lmid[el * 9];
#pragma unroll
        for (int d = 0; d < 9; ++d) ls[d] = fc * (ls[d] + mg[d]);
    }
    __syncthreads();

    // GatedMLP epilogue: wave per edge, lane = feature; LDS + streamed attr/out only.
    int wid  = threadIdx.x >> 6;
    int lane = threadIdx.x & 63;
    int nw   = blockDim.x >> 6;
    for (int el = wid; el < ecnt; el += nw) {
        int e = ebase + el;
        const float* ls = &lmid[el * 9];
        float am = sbm[lane], ag = sbg[lane];
#pragma unroll
        for (int d = 0; d < 9; ++d) {
            float ud = ls[d];
            am += ud * sWm[d * 64 + lane];
            ag += ud * sWg[d * 64 + lane];
        }
        float h  = am / (1.0f + __expf(-am));   // silu
        float gt = 1.0f / (1.0f + __expf(-ag)); // sigmoid
        size_t off = (size_t)e * 64 + lane;
        out[off] = attr[off] + h * gt;
    }
}

// ---------------- Legacy fallback triplet kernel (round-1 path, f32 gate) ----------------
__global__ void triplet_kernel(const float* __restrict__ dist,
                               const float* __restrict__ ang,
                               const int* __restrict__ tidx,
                               const int* __restrict__ eidx,
                               const float* __restrict__ gate,
                               float* __restrict__ mid,
                               int T, int E) {
    int t = blockIdx.x * blockDim.x + threadIdx.x;
    if (t >= T) return;
    int ij = tidx[t];
    int ik = tidx[T + t];
    float ca  = ang[t];
    float rij = dist[ij];
    float rik = dist[ik];
    float frij = fcut(rij);
    int nk = eidx[E + ik];
    const float* g = gate + (size_t)nk * 9;
    float vr[9];
    radial9(rik, vr);   // includes fc(rik)
    float s0, s1, s2;
    legendre_s(ca, s0, s1, s2);
    s0 *= frij; s1 *= frij; s2 *= frij;
    float* dst = mid + (size_t)ij * 9;
    atomicAdd(dst + 0, vr[0] * s0 * g[0]);
    atomicAdd(dst + 1, vr[1] * s0 * g[1]);
    atomicAdd(dst + 2, vr[2] * s0 * g[2]);
    atomicAdd(dst + 3, vr[3] * s1 * g[3]);
    atomicAdd(dst + 4, vr[4] * s1 * g[4]);
    atomicAdd(dst + 5, vr[5] * s1 * g[5]);
    atomicAdd(dst + 6, vr[6] * s2 * g[6]);
    atomicAdd(dst + 7, vr[7] * s2 * g[7]);
    atomicAdd(dst + 8, vr[8] * s2 * g[8]);
}

// ---------------- Legacy Stage 3 (fallback path only) ----------------
__global__ void edge_kernel(const float* __restrict__ mid,
                            const float* __restrict__ attr,
                            const float* __restrict__ Wm, const float* __restrict__ bm,
                            const float* __restrict__ Wg, const float* __restrict__ bg,
                            float* __restrict__ out, int E) {
    __shared__ float sWm[9 * 64], sWg[9 * 64], sbm[64], sbg[64];
    for (int i = threadIdx.x; i < 576; i += blockDim.x) {
        sWm[i] = Wm[i];
        sWg[i] = Wg[i];
    }
    if (threadIdx.x < 64) {
        sbm[threadIdx.x] = bm[threadIdx.x];
        sbg[threadIdx.x] = bg[threadIdx.x];
    }
    __syncthreads();
    int wid  = threadIdx.x >> 6;
    int lane = threadIdx.x & 63;
    int e = blockIdx.x * (blockDim.x >> 6) + wid;
    if (e >= E) return;
    const float* u = mid + (size_t)e * 9;
    float am = sbm[lane], ag = sbg[lane];
#pragma unroll
    for (int d = 0; d < 9; ++d) {
        float ud = u[d];
        am += ud * sWm[d * 64 + lane];
        ag += ud * sWg[d * 64 + lane];
    }
    float h  = am / (1.0f + __expf(-am));
    float gt = 1.0f / (1.0f + __expf(-ag));
    size_t off = (size_t)e * 64 + lane;
    out[off] = attr[off] + h * gt;
}

extern "C" void kernel_launch(void* const* d_in, const int* in_sizes, int n_in,
                              void* d_out, int out_size, void* d_ws, size_t ws_size,
                              hipStream_t stream) {
    const float* dist = (const float*)d_in[0];
    const float* ang  = (const float*)d_in[1];
    const float* nf   = (const float*)d_in[2];
    const float* attr = (const float*)d_in[3];
    const float* W1   = (const float*)d_in[4];
    const float* b1   = (const float*)d_in[5];
    const float* Wm   = (const float*)d_in[6];
    const float* bm   = (const float*)d_in[7];
    const float* Wg   = (const float*)d_in[8];
    const float* bg   = (const float*)d_in[9];
    const int* tidx   = (const int*)d_in[10];
    const int* eidx   = (const int*)d_in[11];

    int E = in_sizes[0];
    int T = in_sizes[1];
    int N = in_sizes[2] / 64;

    int NBIN = (E + EPB - 1) >> EPB_SHIFT;
    int mean = T / (NBIN > 0 ? NBIN : 1);
    int BCAP = ((mean + mean / 8 + 512) + 15) & ~15;   // ~20 sigma headroom, 16-aligned

    // ws layout (4B units): gate16h[N*8] | tab[E] | mid[E*9] | gcount[NBIN*16] | binbuf[NBIN*BCAP*2]
    size_t o_gate  = 0;
    size_t o_tab   = o_gate + (size_t)N * 8;
    size_t o_mid   = o_tab + (size_t)E;
    size_t o_gcnt  = o_mid + (size_t)E * 9;
    size_t o_bb    = (o_gcnt + (size_t)NBIN * GC_STRIDE + 15) & ~(size_t)15;  // 64B-align binbuf
    size_t total   = o_bb + (size_t)NBIN * BCAP * 2;

    bool newpath = (E <= (1 << 20)) && (N <= 65535) && (NBIN <= NBIN_MAX)
                   && (NBIN <= P1_THREADS) && (ws_size >= total * 4);

    float* wsf = (float*)d_ws;

    if (newpath) {
        uint*  gate16h = (uint*)(wsf + o_gate);
        uint*  tab     = (uint*)(wsf + o_tab);
        float* mid     = wsf + o_mid;
        uint*  gcount  = (uint*)(wsf + o_gcnt);
        uint2* binbuf  = (uint2*)(wsf + o_bb);

        hipMemsetAsync(gcount, 0, (size_t)NBIN * GC_STRIDE * sizeof(uint), stream);
        hipMemsetAsync(mid, 0, (size_t)E * 9 * sizeof(float), stream);
        node_gate_h16_kernel<<<(N + 255) / 256, 256, 0, stream>>>(nf, W1, b1, gate16h, N);
        edge_tab_kernel<<<(E + 255) / 256, 256, 0, stream>>>(dist, eidx, tab, E);

        int p1grid = (T + P1_CHUNK - 1) / P1_CHUNK;
        p1_sort_kernel<<<p1grid, P1_THREADS, 0, stream>>>(ang, tidx, tab, gcount, binbuf,
                                                          gate16h, mid, T, NBIN, BCAP);
        p2_fused_kernel<<<NBIN, 1024, 0, stream>>>(dist, gate16h, gcount, binbuf, mid,
                                                   attr, Wm, bm, Wg, bg,
                                                   (float*)d_out, E, BCAP);
    } else {
        // legacy path (round-1)
        float* gate = wsf;
        float* mid = gate + (((size_t)N * 9 + 15) & ~(size_t)15);
        hipMemsetAsync(mid, 0, (size_t)E * 9 * sizeof(float), stream);
        node_gate_f32_kernel<<<(N + 255) / 256, 256, 0, stream>>>(nf, W1, b1, gate, N);
        triplet_kernel<<<(T + 255) / 256, 256, 0, stream>>>(dist, ang, tidx, eidx, gate, mid, T, E);
        edge_kernel<<<(E + 3) / 4, 256, 0, stream>>>(mid, attr, Wm, bm, Wg, bg, (float*)d_out, E);
    }
}

// Round 10
// 700.306 us; speedup vs baseline: 1.0478x; 1.0371x over previous
//
#include <hip/hip_runtime.h>
#include <hip/hip_fp16.h>
#include <math.h>

#define CUTOFF_INV 0.2f
#define EPB_SHIFT 10
#define EPB 1024
#define NBIN_MAX 1024
#define P1_CHUNK 4096
#define P1_THREADS 1024
#define P2_THREADS 512
#define GC_STRIDE 16   // gcount padding: 64B per counter; [.. +1] = overflow flag

typedef unsigned int uint;
typedef unsigned short ushort;

__device__ __forceinline__ float fcut(float r) {
    // 1 - 6p^5 + 15p^4 - 10p^3, p = r/cutoff
    float p = r * CUTOFF_INV;
    float p2 = p * p;
    float p3 = p2 * p;
    return 1.0f + p3 * (-10.0f + p * (15.0f - 6.0f * p));
}

// spherical-plus-norm legendre factors: s_l = sqrt((2l+1)/pi) * P_l(ca)
__device__ __forceinline__ void legendre_s(float ca, float& s0, float& s1, float& s2) {
    s0 = 0.5641895835477563f;
    s1 = 0.9772050238058398f * ca;
    s2 = 1.2615662610100802f * (1.5f * ca * ca - 0.5f);
}

// radial part, divide-free: one v_rcp + NR, all 1/x via inv * (1/Z) const-folded.
// v[l*3+n] = j_l(z_{l,n} * rik / cutoff) * fc(rik)
__device__ __forceinline__ void radial9(float rik, float* v) {
    float rr = rik * CUTOFF_INV;           // (0, 1]
    float inv = __builtin_amdgcn_rcpf(rr);
    inv = inv * (2.0f - rr * inv);         // one NR refine
    float fcik = fcut(rik);

    const float Z0[3]  = {3.14159265358979324f, 6.28318530717958648f, 9.42477796076937972f};
    const float IZ0[3] = {1.0f / 3.14159265358979324f, 1.0f / 6.28318530717958648f, 1.0f / 9.42477796076937972f};
    const float Z1[3]  = {4.49340945790806150f, 7.72525183693865170f, 10.9041216594298970f};
    const float IZ1[3] = {1.0f / 4.49340945790806150f, 1.0f / 7.72525183693865170f, 1.0f / 10.9041216594298970f};
    const float Z2[3]  = {5.76345919689554900f, 9.09501133047736000f, 12.3229409705673230f};
    const float IZ2[3] = {1.0f / 5.76345919689554900f, 1.0f / 9.09501133047736000f, 1.0f / 12.3229409705673230f};

#pragma unroll
    for (int n = 0; n < 3; ++n) {          // l = 0: j0 = sin(x) * invx
        float x = Z0[n] * rr;
        float invx = IZ0[n] * inv;
        v[n] = __sinf(x) * invx * fcik;
    }
#pragma unroll
    for (int n = 0; n < 3; ++n) {          // l = 1: j1 = (sin*invx - cos)*invx
        float x = Z1[n] * rr;
        float invx = IZ1[n] * inv;
        float s, c;
        __sincosf(x, &s, &c);
        v[3 + n] = (s * invx - c) * invx * fcik;
    }
#pragma unroll
    for (int n = 0; n < 3; ++n) {          // l = 2: j2 = 3*invx*j1 - j0
        float x = Z2[n] * rr;
        float invx = IZ2[n] * inv;
        float s, c;
        __sincosf(x, &s, &c);
        float sx = s * invx;
        float j1 = (sx - c) * invx;
        v[6 + n] = (3.0f * invx * j1 - sx) * fcik;
    }
}

__device__ __forceinline__ float h2f(uint w) { return __half2float(__ushort_as_half((ushort)w)); }

// ---------------- Stage 1 (new path): node gate -> packed f16 rows [N][8 uints] (32B) ----------------
__global__ void node_gate_h16_kernel(const float* __restrict__ nf,
                                     const float* __restrict__ W1,
                                     const float* __restrict__ b1,
                                     uint* __restrict__ gate16h, int N) {
    __shared__ float sW[64 * 9];
    __shared__ float sb[9];
    for (int i = threadIdx.x; i < 576; i += blockDim.x) sW[i] = W1[i];
    if (threadIdx.x < 9) sb[threadIdx.x] = b1[threadIdx.x];
    __syncthreads();
    int t = blockIdx.x * blockDim.x + threadIdx.x;
    if (t >= N) return;
    float acc[9];
#pragma unroll
    for (int d = 0; d < 9; ++d) acc[d] = sb[d];
    const float* row = nf + (size_t)t * 64;
#pragma unroll
    for (int f = 0; f < 64; ++f) {
        float x = row[f];
#pragma unroll
        for (int d = 0; d < 9; ++d) acc[d] += x * sW[f * 9 + d];
    }
    float g[9];
#pragma unroll
    for (int d = 0; d < 9; ++d) g[d] = 1.0f / (1.0f + __expf(-acc[d]));
    uint* o = gate16h + ((size_t)t << 3);
#pragma unroll
    for (int d = 0; d < 4; ++d) {
        uint lo = (uint)__half_as_ushort(__float2half_rn(g[2 * d]));
        uint hi = (uint)__half_as_ushort(__float2half_rn(g[2 * d + 1]));
        o[d] = lo | (hi << 16);
    }
    o[4] = (uint)__half_as_ushort(__float2half_rn(g[8]));
    o[5] = 0u; o[6] = 0u; o[7] = 0u;
}

// ---------------- Stage 1 (legacy path): f32 gate [N,9] ----------------
__global__ void node_gate_f32_kernel(const float* __restrict__ nf,
                                     const float* __restrict__ W1,
                                     const float* __restrict__ b1,
                                     float* __restrict__ gate, int N) {
    __shared__ float sW[64 * 9];
    __shared__ float sb[9];
    for (int i = threadIdx.x; i < 576; i += blockDim.x) sW[i] = W1[i];
    if (threadIdx.x < 9) sb[threadIdx.x] = b1[threadIdx.x];
    __syncthreads();
    int t = blockIdx.x * blockDim.x + threadIdx.x;
    if (t >= N) return;
    float acc[9];
#pragma unroll
    for (int d = 0; d < 9; ++d) acc[d] = sb[d];
    const float* row = nf + (size_t)t * 64;
#pragma unroll
    for (int f = 0; f < 64; ++f) {
        float x = row[f];
#pragma unroll
        for (int d = 0; d < 9; ++d) acc[d] += x * sW[f * 9 + d];
    }
#pragma unroll
    for (int d = 0; d < 9; ++d)
        gate[(size_t)t * 9 + d] = 1.0f / (1.0f + __expf(-acc[d]));
}

// ---------------- Stage 2a: per-edge packed table tab[e] = (f16(rik) << 16) | nk ----------------
__global__ void edge_tab_kernel(const float* __restrict__ dist,
                                const int* __restrict__ eidx,   // [2,E]
                                uint* __restrict__ tab, int E) {
    int e = blockIdx.x * blockDim.x + threadIdx.x;
    if (e >= E) return;
    uint rh = (uint)__half_as_ushort(__float2half_rn(dist[e]));
    tab[e] = (rh << 16) | (uint)eidx[E + e];
}

// overflow fallback: accumulate one record straight into global mid
__device__ __forceinline__ void spill_rec(uint2 rec, int bin,
                                          const uint* __restrict__ gate16h,
                                          float* __restrict__ mid) {
    float ca  = h2f(rec.x >> 16);
    float rik = h2f(rec.x & 0xFFFFu);
    uint nk  = rec.y & 0xFFFFu;
    uint ijl = rec.y >> 16;
    float vr[9];
    radial9(rik, vr);
    const uint* gr = gate16h + ((size_t)nk << 3);
    uint4 q = *(const uint4*)gr;
    uint q8 = gr[4];
    float s0, s1, s2;
    legendre_s(ca, s0, s1, s2);
    float* dst = mid + ((size_t)bin * EPB + ijl) * 9;
    atomicAdd(dst + 0, vr[0] * h2f(q.x & 0xFFFFu) * s0);
    atomicAdd(dst + 1, vr[1] * h2f(q.x >> 16) * s0);
    atomicAdd(dst + 2, vr[2] * h2f(q.y & 0xFFFFu) * s0);
    atomicAdd(dst + 3, vr[3] * h2f(q.y >> 16) * s1);
    atomicAdd(dst + 4, vr[4] * h2f(q.z & 0xFFFFu) * s1);
    atomicAdd(dst + 5, vr[5] * h2f(q.z >> 16) * s1);
    atomicAdd(dst + 6, vr[6] * h2f(q.w & 0xFFFFu) * s2);
    atomicAdd(dst + 7, vr[7] * h2f(q.w >> 16) * s2);
    atomicAdd(dst + 8, vr[8] * h2f(q8 & 0xFFFFu) * s2);
}

// ---------------- Pass 1: block-local counting sort -> binned self-contained records ----------------
// record = {ca_f16<<16 | rik_f16, ijl<<16 | nk}. One 4B gather from the 4MB tab per triplet.
__global__ void __launch_bounds__(P1_THREADS) p1_sort_kernel(
        const float* __restrict__ ang,
        const int* __restrict__ tidx, // [2,T]
        const uint* __restrict__ tab, // [E]
        uint* __restrict__ gcount,    // [NBIN*GC_STRIDE]
        uint2* __restrict__ binbuf,   // [NBIN*BCAP]
        const uint* __restrict__ gate16h,
        float* __restrict__ mid,
        int T, int NBIN, int BCAP) {
    __shared__ uint hist[NBIN_MAX];
    __shared__ uint sc[NBIN_MAX];     // inclusive scan -> exclusive prefix
    __shared__ uint gbase[NBIN_MAX];
    __shared__ uint lcur[NBIN_MAX];
    __shared__ uint2 sbuf[P1_CHUNK];
    __shared__ ushort sbin[P1_CHUNK];

    int t0 = blockIdx.x * P1_CHUNK;
    int m = T - t0;
    if (m <= 0) return;
    if (m > P1_CHUNK) m = P1_CHUNK;
    int tid = threadIdx.x;

    for (int i = tid; i < NBIN; i += blockDim.x) { hist[i] = 0; lcur[i] = 0; }
    __syncthreads();

    // pass A: histogram (reads tidx row 0 only)
    for (int i = tid; i < m; i += blockDim.x)
        atomicAdd(&hist[((uint)tidx[t0 + i]) >> EPB_SHIFT], 1u);
    __syncthreads();

    // inclusive scan of hist into sc (NBIN <= blockDim)
    if (tid < NBIN) sc[tid] = hist[tid];
    __syncthreads();
    for (int off = 1; off < NBIN; off <<= 1) {
        uint v = 0;
        if (tid < NBIN) {
            v = sc[tid];
            if (tid >= off) v += sc[tid - off];
        }
        __syncthreads();
        if (tid < NBIN) sc[tid] = v;
        __syncthreads();
    }
    // exclusive prefix + global reservation
    uint ex = 0, h = 0;
    if (tid < NBIN) {
        h = hist[tid];
        ex = sc[tid] - h;
    }
    __syncthreads();
    if (tid < NBIN) {
        sc[tid] = ex;
        gbase[tid] = h ? atomicAdd(&gcount[tid * GC_STRIDE], h) : 0u;
    }
    __syncthreads();

    // pass B: build records (tab gather: 4B from L2-hot 4MB), place sorted by bin
    for (int i = tid; i < m; i += blockDim.x) {
        int t = t0 + i;
        uint ij = (uint)tidx[t];
        uint ik = (uint)tidx[T + t];
        float ca = ang[t];
        uint te = tab[ik];   // (rik_f16 << 16) | nk
        uint bin = ij >> EPB_SHIFT;
        uint loc = atomicAdd(&lcur[bin], 1u);
        uint p = sc[bin] + loc;
        uint cah = (uint)__half_as_ushort(__float2half_rn(ca));
        sbuf[p] = make_uint2((cah << 16) | (te >> 16),
                             ((ij & (EPB - 1u)) << 16) | (te & 0xFFFFu));
        sbin[p] = (ushort)bin;
    }
    __syncthreads();

    // pass C: coalesced writeout of sorted runs
    for (int i = tid; i < m; i += blockDim.x) {
        uint bin = sbin[i];
        uint2 rec = sbuf[i];
        uint slot = gbase[bin] + ((uint)i - sc[bin]);
        if (slot < (uint)BCAP) {
            binbuf[(size_t)bin * BCAP + slot] = rec;
        } else {
            atomicOr(&gcount[bin * GC_STRIDE + 1], 1u);   // overflow flag
            spill_rec(rec, bin, gate16h, mid);
        }
    }
}

// ---------------- Pass 2 (fused): per-bin accumulate in LDS, merge, GatedMLP epilogue ----------------
// 512 threads, EPB=1024 -> ~42KB LDS -> 3 blocks/CU (24 waves) vs prior ~1 (15).
__global__ void __launch_bounds__(P2_THREADS) p2_fused_kernel(const float* __restrict__ dist,
                                                        const uint* __restrict__ gate16h, // [N,8]
                                                        const uint* __restrict__ gcount,  // [NBIN*GC_STRIDE]
                                                        const uint2* __restrict__ binbuf,
                                                        const float* __restrict__ mid,    // [E,9] spill acc
                                                        const float* __restrict__ attr,
                                                        const float* __restrict__ Wm,
                                                        const float* __restrict__ bm,
                                                        const float* __restrict__ Wg,
                                                        const float* __restrict__ bg,
                                                        float* __restrict__ out,
                                                        int E, int BCAP) {
    __shared__ float lmid[EPB * 9];   // 36 KB
    __shared__ float sWm[576], sWg[576], sbm[64], sbg[64];
    for (int i = threadIdx.x; i < 576; i += blockDim.x) {
        sWm[i] = Wm[i];
        sWg[i] = Wg[i];
    }
    if (threadIdx.x < 64) {
        sbm[threadIdx.x] = bm[threadIdx.x];
        sbg[threadIdx.x] = bg[threadIdx.x];
    }
    int b = blockIdx.x;
    int ebase = b << EPB_SHIFT;
    int ecnt = min(EPB, E - ebase);
    for (int i = threadIdx.x; i < EPB * 9; i += blockDim.x) lmid[i] = 0.0f;
    __syncthreads();

    uint n = gcount[b * GC_STRIDE];
    uint has_spill = gcount[b * GC_STRIDE + 1];
    if (n > (uint)BCAP) n = (uint)BCAP;
    const uint2* rb = binbuf + (size_t)b * BCAP;
    uint bd = blockDim.x;
    uint i = threadIdx.x;

#define ACC_ONE(rr_, q_, q8_)                                         \
    {                                                                 \
        float ca  = h2f(rr_.x >> 16);                                 \
        float rik = h2f(rr_.x & 0xFFFFu);                             \
        uint ijl = rr_.y >> 16;                                       \
        float vr[9];                                                  \
        radial9(rik, vr);                                             \
        float s0, s1, s2;                                             \
        legendre_s(ca, s0, s1, s2);                                   \
        float* d = &lmid[ijl * 9];                                    \
        atomicAdd(d + 0, vr[0] * h2f(q_.x & 0xFFFFu) * s0);           \
        atomicAdd(d + 1, vr[1] * h2f(q_.x >> 16) * s0);               \
        atomicAdd(d + 2, vr[2] * h2f(q_.y & 0xFFFFu) * s0);           \
        atomicAdd(d + 3, vr[3] * h2f(q_.y >> 16) * s1);               \
        atomicAdd(d + 4, vr[4] * h2f(q_.z & 0xFFFFu) * s1);           \
        atomicAdd(d + 5, vr[5] * h2f(q_.z >> 16) * s1);               \
        atomicAdd(d + 6, vr[6] * h2f(q_.w & 0xFFFFu) * s2);           \
        atomicAdd(d + 7, vr[7] * h2f(q_.w >> 16) * s2);               \
        atomicAdd(d + 8, vr[8] * h2f(q8_ & 0xFFFFu) * s2);            \
    }

    for (; i + 3 * bd < n; i += 4 * bd) {
        uint2 r0 = rb[i];
        uint2 r1 = rb[i + bd];
        uint2 r2 = rb[i + 2 * bd];
        uint2 r3 = rb[i + 3 * bd];
        const uint* G0 = gate16h + ((size_t)(r0.y & 0xFFFFu) << 3);
        const uint* G1 = gate16h + ((size_t)(r1.y & 0xFFFFu) << 3);
        const uint* G2 = gate16h + ((size_t)(r2.y & 0xFFFFu) << 3);
        const uint* G3 = gate16h + ((size_t)(r3.y & 0xFFFFu) << 3);
        uint4 q0 = *(const uint4*)G0; uint q08 = G0[4];
        uint4 q1 = *(const uint4*)G1; uint q18 = G1[4];
        uint4 q2 = *(const uint4*)G2; uint q28 = G2[4];
        uint4 q3 = *(const uint4*)G3; uint q38 = G3[4];
        ACC_ONE(r0, q0, q08)
        ACC_ONE(r1, q1, q18)
        ACC_ONE(r2, q2, q28)
        ACC_ONE(r3, q3, q38)
    }
    for (; i < n; i += bd) {
        uint2 rr = rb[i];
        const uint* G = gate16h + ((size_t)(rr.y & 0xFFFFu) << 3);
        uint4 q = *(const uint4*)G; uint q8 = G[4];
        ACC_ONE(rr, q, q8)
    }
#undef ACC_ONE

    __syncthreads();
    // merge pass: fold fc(rij) (and spill-mid only when the bin overflowed)
    if (has_spill) {
        for (int el = threadIdx.x; el < ecnt; el += blockDim.x) {
            int e = ebase + el;
            float fc = fcut(dist[e]);
            const float* mg = mid + (size_t)e * 9;
            float* ls = &lmid[el * 9];
#pragma unroll
            for (int d = 0; d < 9; ++d) ls[d] = fc * (ls[d] + mg[d]);
        }
    } else {
        for (int el = threadIdx.x; el < ecnt; el += blockDim.x) {
            int e = ebase + el;
            float fc = fcut(dist[e]);
            float* ls = &lmid[el * 9];
#pragma unroll
            for (int d = 0; d < 9; ++d) ls[d] = fc * ls[d];
        }
    }
    __syncthreads();

    // GatedMLP epilogue: wave per edge, lane = feature; LDS + streamed attr/out only.
    int wid  = threadIdx.x >> 6;
    int lane = threadIdx.x & 63;
    int nw   = blockDim.x >> 6;
    for (int el = wid; el < ecnt; el += nw) {
        int e = ebase + el;
        const float* ls = &lmid[el * 9];
        float am = sbm[lane], ag = sbg[lane];
#pragma unroll
        for (int d = 0; d < 9; ++d) {
            float ud = ls[d];
            am += ud * sWm[d * 64 + lane];
            ag += ud * sWg[d * 64 + lane];
        }
        float h  = am / (1.0f + __expf(-am));   // silu
        float gt = 1.0f / (1.0f + __expf(-ag)); // sigmoid
        size_t off = (size_t)e * 64 + lane;
        out[off] = attr[off] + h * gt;
    }
}

// ---------------- Legacy fallback triplet kernel (round-1 path, f32 gate) ----------------
__global__ void triplet_kernel(const float* __restrict__ dist,
                               const float* __restrict__ ang,
                               const int* __restrict__ tidx,
                               const int* __restrict__ eidx,
                               const float* __restrict__ gate,
                               float* __restrict__ mid,
                               int T, int E) {
    int t = blockIdx.x * blockDim.x + threadIdx.x;
    if (t >= T) return;
    int ij = tidx[t];
    int ik = tidx[T + t];
    float ca  = ang[t];
    float rij = dist[ij];
    float rik = dist[ik];
    float frij = fcut(rij);
    int nk = eidx[E + ik];
    const float* g = gate + (size_t)nk * 9;
    float vr[9];
    radial9(rik, vr);   // includes fc(rik)
    float s0, s1, s2;
    legendre_s(ca, s0, s1, s2);
    s0 *= frij; s1 *= frij; s2 *= frij;
    float* dst = mid + (size_t)ij * 9;
    atomicAdd(dst + 0, vr[0] * s0 * g[0]);
    atomicAdd(dst + 1, vr[1] * s0 * g[1]);
    atomicAdd(dst + 2, vr[2] * s0 * g[2]);
    atomicAdd(dst + 3, vr[3] * s1 * g[3]);
    atomicAdd(dst + 4, vr[4] * s1 * g[4]);
    atomicAdd(dst + 5, vr[5] * s1 * g[5]);
    atomicAdd(dst + 6, vr[6] * s2 * g[6]);
    atomicAdd(dst + 7, vr[7] * s2 * g[7]);
    atomicAdd(dst + 8, vr[8] * s2 * g[8]);
}

// ---------------- Legacy Stage 3 (fallback path only) ----------------
__global__ void edge_kernel(const float* __restrict__ mid,
                            const float* __restrict__ attr,
                            const float* __restrict__ Wm, const float* __restrict__ bm,
                            const float* __restrict__ Wg, const float* __restrict__ bg,
                            float* __restrict__ out, int E) {
    __shared__ float sWm[9 * 64], sWg[9 * 64], sbm[64], sbg[64];
    for (int i = threadIdx.x; i < 576; i += blockDim.x) {
        sWm[i] = Wm[i];
        sWg[i] = Wg[i];
    }
    if (threadIdx.x < 64) {
        sbm[threadIdx.x] = bm[threadIdx.x];
        sbg[threadIdx.x] = bg[threadIdx.x];
    }
    __syncthreads();
    int wid  = threadIdx.x >> 6;
    int lane = threadIdx.x & 63;
    int e = blockIdx.x * (blockDim.x >> 6) + wid;
    if (e >= E) return;
    const float* u = mid + (size_t)e * 9;
    float am = sbm[lane], ag = sbg[lane];
#pragma unroll
    for (int d = 0; d < 9; ++d) {
        float ud = u[d];
        am += ud * sWm[d * 64 + lane];
        ag += ud * sWg[d * 64 + lane];
    }
    float h  = am / (1.0f + __expf(-am));
    float gt = 1.0f / (1.0f + __expf(-ag));
    size_t off = (size_t)e * 64 + lane;
    out[off] = attr[off] + h * gt;
}

extern "C" void kernel_launch(void* const* d_in, const int* in_sizes, int n_in,
                              void* d_out, int out_size, void* d_ws, size_t ws_size,
                              hipStream_t stream) {
    const float* dist = (const float*)d_in[0];
    const float* ang  = (const float*)d_in[1];
    const float* nf   = (const float*)d_in[2];
    const float* attr = (const float*)d_in[3];
    const float* W1   = (const float*)d_in[4];
    const float* b1   = (const float*)d_in[5];
    const float* Wm   = (const float*)d_in[6];
    const float* bm   = (const float*)d_in[7];
    const float* Wg   = (const float*)d_in[8];
    const float* bg   = (const float*)d_in[9];
    const int* tidx   = (const int*)d_in[10];
    const int* eidx   = (const int*)d_in[11];

    int E = in_sizes[0];
    int T = in_sizes[1];
    int N = in_sizes[2] / 64;

    int NBIN = (E + EPB - 1) >> EPB_SHIFT;
    int mean = T / (NBIN > 0 ? NBIN : 1);

    // two BCAP tiers, graceful fallback on ws size
    int bcap1 = ((mean + mean / 8 + 512) + 15) & ~15;
    int bcap2 = ((mean + mean / 32 + 256) + 15) & ~15;

    size_t o_gate  = 0;
    size_t o_tab   = o_gate + (size_t)N * 8;
    size_t o_mid   = o_tab + (size_t)E;
    size_t o_gcnt  = o_mid + (size_t)E * 9;
    size_t o_bb    = (o_gcnt + (size_t)NBIN * GC_STRIDE + 15) & ~(size_t)15;  // 64B-align binbuf
    auto need = [&](int cap) { return (o_bb + (size_t)NBIN * cap * 2) * 4; };

    int BCAP = 0;
    if (ws_size >= need(bcap1)) BCAP = bcap1;
    else if (ws_size >= need(bcap2)) BCAP = bcap2;

    bool newpath = (E <= (1 << 20)) && (N <= 65535) && (NBIN <= NBIN_MAX)
                   && (NBIN <= P1_THREADS) && (BCAP > 0);

    float* wsf = (float*)d_ws;

    if (newpath) {
        uint*  gate16h = (uint*)(wsf + o_gate);
        uint*  tab     = (uint*)(wsf + o_tab);
        float* mid     = wsf + o_mid;
        uint*  gcount  = (uint*)(wsf + o_gcnt);
        uint2* binbuf  = (uint2*)(wsf + o_bb);

        hipMemsetAsync(gcount, 0, (size_t)NBIN * GC_STRIDE * sizeof(uint), stream);
        hipMemsetAsync(mid, 0, (size_t)E * 9 * sizeof(float), stream);
        node_gate_h16_kernel<<<(N + 255) / 256, 256, 0, stream>>>(nf, W1, b1, gate16h, N);
        edge_tab_kernel<<<(E + 255) / 256, 256, 0, stream>>>(dist, eidx, tab, E);

        int p1grid = (T + P1_CHUNK - 1) / P1_CHUNK;
        p1_sort_kernel<<<p1grid, P1_THREADS, 0, stream>>>(ang, tidx, tab, gcount, binbuf,
                                                          gate16h, mid, T, NBIN, BCAP);
        p2_fused_kernel<<<NBIN, P2_THREADS, 0, stream>>>(dist, gate16h, gcount, binbuf, mid,
                                                         attr, Wm, bm, Wg, bg,
                                                         (float*)d_out, E, BCAP);
    } else {
        // legacy path (round-1)
        float* gate = wsf;
        float* mid = gate + (((size_t)N * 9 + 15) & ~(size_t)15);
        hipMemsetAsync(mid, 0, (size_t)E * 9 * sizeof(float), stream);
        node_gate_f32_kernel<<<(N + 255) / 256, 256, 0, stream>>>(nf, W1, b1, gate, N);
        triplet_kernel<<<(T + 255) / 256, 256, 0, stream>>>(dist, ang, tidx, eidx, gate, mid, T, E);
        edge_kernel<<<(E + 3) / 4, 256, 0, stream>>>(mid, attr, Wm, bm, Wg, bg, (float*)d_out, E);
    }
}

// Round 11
// 448.850 us; speedup vs baseline: 1.6348x; 1.5602x over previous
//
#include <hip/hip_runtime.h>
#include <hip/hip_fp16.h>
#include <math.h>

#define CUTOFF_INV 0.2f
#define EPB_SHIFT 10
#define EPB 1024
#define HEPB 512            // edges per p2 block (half a p1 bin)
#define NBIN_MAX 1024
#define P1_CHUNK 4096
#define P1_THREADS 1024
#define P2_THREADS 512
#define SCAP 5120           // LDS sorted-record capacity per half-bin (mean ~4094)
#define GC_STRIDE 16        // gcount padding; [..+1] = overflow flag

typedef unsigned int uint;
typedef unsigned short ushort;

__device__ __forceinline__ float fcut(float r) {
    float p = r * CUTOFF_INV;
    float p2 = p * p;
    float p3 = p2 * p;
    return 1.0f + p3 * (-10.0f + p * (15.0f - 6.0f * p));
}

__device__ __forceinline__ void legendre_s(float ca, float& s0, float& s1, float& s2) {
    s0 = 0.5641895835477563f;
    s1 = 0.9772050238058398f * ca;
    s2 = 1.2615662610100802f * (1.5f * ca * ca - 0.5f);
}

// divide-free radial: v[l*3+n] = j_l(z_{l,n} * rik / cutoff) * fc(rik)
__device__ __forceinline__ void radial9(float rik, float* v) {
    float rr = rik * CUTOFF_INV;
    float inv = __builtin_amdgcn_rcpf(rr);
    inv = inv * (2.0f - rr * inv);
    float fcik = fcut(rik);

    const float Z0[3]  = {3.14159265358979324f, 6.28318530717958648f, 9.42477796076937972f};
    const float IZ0[3] = {1.0f / 3.14159265358979324f, 1.0f / 6.28318530717958648f, 1.0f / 9.42477796076937972f};
    const float Z1[3]  = {4.49340945790806150f, 7.72525183693865170f, 10.9041216594298970f};
    const float IZ1[3] = {1.0f / 4.49340945790806150f, 1.0f / 7.72525183693865170f, 1.0f / 10.9041216594298970f};
    const float Z2[3]  = {5.76345919689554900f, 9.09501133047736000f, 12.3229409705673230f};
    const float IZ2[3] = {1.0f / 5.76345919689554900f, 1.0f / 9.09501133047736000f, 1.0f / 12.3229409705673230f};

#pragma unroll
    for (int n = 0; n < 3; ++n) {
        float x = Z0[n] * rr;
        float invx = IZ0[n] * inv;
        v[n] = __sinf(x) * invx * fcik;
    }
#pragma unroll
    for (int n = 0; n < 3; ++n) {
        float x = Z1[n] * rr;
        float invx = IZ1[n] * inv;
        float s, c;
        __sincosf(x, &s, &c);
        v[3 + n] = (s * invx - c) * invx * fcik;
    }
#pragma unroll
    for (int n = 0; n < 3; ++n) {
        float x = Z2[n] * rr;
        float invx = IZ2[n] * inv;
        float s, c;
        __sincosf(x, &s, &c);
        float sx = s * invx;
        float j1 = (sx - c) * invx;
        v[6 + n] = (3.0f * invx * j1 - sx) * fcik;
    }
}

__device__ __forceinline__ float h2f(uint w) { return __half2float(__ushort_as_half((ushort)w)); }

// full per-record contribution c[9] = vr * gate * s  (gate load issued before compute)
__device__ __forceinline__ void contrib9(uint2 r, const uint* __restrict__ gate16h, float* c) {
    uint nk = r.y & 0xFFFFu;
    const uint* G = gate16h + ((size_t)nk << 3);
    uint4 q = *(const uint4*)G;          // issue gather first
    uint q8 = G[4];
    float ca  = h2f(r.x >> 16);
    float rik = h2f(r.x & 0xFFFFu);
    float vr[9];
    radial9(rik, vr);                    // overlaps with gather latency
    float s0, s1, s2;
    legendre_s(ca, s0, s1, s2);
    c[0] = vr[0] * h2f(q.x & 0xFFFFu) * s0;
    c[1] = vr[1] * h2f(q.x >> 16) * s0;
    c[2] = vr[2] * h2f(q.y & 0xFFFFu) * s0;
    c[3] = vr[3] * h2f(q.y >> 16) * s1;
    c[4] = vr[4] * h2f(q.z & 0xFFFFu) * s1;
    c[5] = vr[5] * h2f(q.z >> 16) * s1;
    c[6] = vr[6] * h2f(q.w & 0xFFFFu) * s2;
    c[7] = vr[7] * h2f(q.w >> 16) * s2;
    c[8] = vr[8] * h2f(q8 & 0xFFFFu) * s2;
}

// ---------------- Stage 1: node gate -> packed f16 rows [N][8 uints] ----------------
__global__ void node_gate_h16_kernel(const float* __restrict__ nf,
                                     const float* __restrict__ W1,
                                     const float* __restrict__ b1,
                                     uint* __restrict__ gate16h, int N) {
    __shared__ float sW[64 * 9];
    __shared__ float sb[9];
    for (int i = threadIdx.x; i < 576; i += blockDim.x) sW[i] = W1[i];
    if (threadIdx.x < 9) sb[threadIdx.x] = b1[threadIdx.x];
    __syncthreads();
    int t = blockIdx.x * blockDim.x + threadIdx.x;
    if (t >= N) return;
    float acc[9];
#pragma unroll
    for (int d = 0; d < 9; ++d) acc[d] = sb[d];
    const float* row = nf + (size_t)t * 64;
#pragma unroll
    for (int f = 0; f < 64; ++f) {
        float x = row[f];
#pragma unroll
        for (int d = 0; d < 9; ++d) acc[d] += x * sW[f * 9 + d];
    }
    float g[9];
#pragma unroll
    for (int d = 0; d < 9; ++d) g[d] = 1.0f / (1.0f + __expf(-acc[d]));
    uint* o = gate16h + ((size_t)t << 3);
#pragma unroll
    for (int d = 0; d < 4; ++d) {
        uint lo = (uint)__half_as_ushort(__float2half_rn(g[2 * d]));
        uint hi = (uint)__half_as_ushort(__float2half_rn(g[2 * d + 1]));
        o[d] = lo | (hi << 16);
    }
    o[4] = (uint)__half_as_ushort(__float2half_rn(g[8]));
    o[5] = 0u; o[6] = 0u; o[7] = 0u;
}

// ---------------- Stage 1 (legacy): f32 gate [N,9] ----------------
__global__ void node_gate_f32_kernel(const float* __restrict__ nf,
                                     const float* __restrict__ W1,
                                     const float* __restrict__ b1,
                                     float* __restrict__ gate, int N) {
    __shared__ float sW[64 * 9];
    __shared__ float sb[9];
    for (int i = threadIdx.x; i < 576; i += blockDim.x) sW[i] = W1[i];
    if (threadIdx.x < 9) sb[threadIdx.x] = b1[threadIdx.x];
    __syncthreads();
    int t = blockIdx.x * blockDim.x + threadIdx.x;
    if (t >= N) return;
    float acc[9];
#pragma unroll
    for (int d = 0; d < 9; ++d) acc[d] = sb[d];
    const float* row = nf + (size_t)t * 64;
#pragma unroll
    for (int f = 0; f < 64; ++f) {
        float x = row[f];
#pragma unroll
        for (int d = 0; d < 9; ++d) acc[d] += x * sW[f * 9 + d];
    }
#pragma unroll
    for (int d = 0; d < 9; ++d)
        gate[(size_t)t * 9 + d] = 1.0f / (1.0f + __expf(-acc[d]));
}

// ---------------- Stage 2a: tab[e] = (f16(rik) << 16) | nk ----------------
__global__ void edge_tab_kernel(const float* __restrict__ dist,
                                const int* __restrict__ eidx,
                                uint* __restrict__ tab, int E) {
    int e = blockIdx.x * blockDim.x + threadIdx.x;
    if (e >= E) return;
    uint rh = (uint)__half_as_ushort(__float2half_rn(dist[e]));
    tab[e] = (rh << 16) | (uint)eidx[E + e];
}

// overflow fallback: accumulate one record straight into global mid
__device__ __forceinline__ void spill_rec(uint2 rec, int bin,
                                          const uint* __restrict__ gate16h,
                                          float* __restrict__ mid) {
    float c[9];
    contrib9(rec, gate16h, c);
    uint ijl = rec.y >> 16;
    float* dst = mid + ((size_t)bin * EPB + ijl) * 9;
#pragma unroll
    for (int d = 0; d < 9; ++d) atomicAdd(dst + d, c[d]);
}

// ---------------- Pass 1: block-local counting sort -> binned records ----------------
__global__ void __launch_bounds__(P1_THREADS) p1_sort_kernel(
        const float* __restrict__ ang,
        const int* __restrict__ tidx, // [2,T]
        const uint* __restrict__ tab, // [E]
        uint* __restrict__ gcount,    // [NBIN*GC_STRIDE]
        uint2* __restrict__ binbuf,   // [NBIN*BCAP]
        const uint* __restrict__ gate16h,
        float* __restrict__ mid,
        int T, int NBIN, int BCAP) {
    __shared__ uint hist[NBIN_MAX];
    __shared__ uint sc[NBIN_MAX];
    __shared__ uint gbase[NBIN_MAX];
    __shared__ uint lcur[NBIN_MAX];
    __shared__ uint2 sbuf[P1_CHUNK];
    __shared__ ushort sbin[P1_CHUNK];

    int t0 = blockIdx.x * P1_CHUNK;
    int m = T - t0;
    if (m <= 0) return;
    if (m > P1_CHUNK) m = P1_CHUNK;
    int tid = threadIdx.x;

    for (int i = tid; i < NBIN; i += blockDim.x) { hist[i] = 0; lcur[i] = 0; }
    __syncthreads();

    for (int i = tid; i < m; i += blockDim.x)
        atomicAdd(&hist[((uint)tidx[t0 + i]) >> EPB_SHIFT], 1u);
    __syncthreads();

    if (tid < NBIN) sc[tid] = hist[tid];
    __syncthreads();
    for (int off = 1; off < NBIN; off <<= 1) {
        uint v = 0;
        if (tid < NBIN) {
            v = sc[tid];
            if (tid >= off) v += sc[tid - off];
        }
        __syncthreads();
        if (tid < NBIN) sc[tid] = v;
        __syncthreads();
    }
    uint ex = 0, h = 0;
    if (tid < NBIN) {
        h = hist[tid];
        ex = sc[tid] - h;
    }
    __syncthreads();
    if (tid < NBIN) {
        sc[tid] = ex;
        gbase[tid] = h ? atomicAdd(&gcount[tid * GC_STRIDE], h) : 0u;
    }
    __syncthreads();

    for (int i = tid; i < m; i += blockDim.x) {
        int t = t0 + i;
        uint ij = (uint)tidx[t];
        uint ik = (uint)tidx[T + t];
        float ca = ang[t];
        uint te = tab[ik];
        uint bin = ij >> EPB_SHIFT;
        uint loc = atomicAdd(&lcur[bin], 1u);
        uint p = sc[bin] + loc;
        uint cah = (uint)__half_as_ushort(__float2half_rn(ca));
        sbuf[p] = make_uint2((cah << 16) | (te >> 16),
                             ((ij & (EPB - 1u)) << 16) | (te & 0xFFFFu));
        sbin[p] = (ushort)bin;
    }
    __syncthreads();

    for (int i = tid; i < m; i += blockDim.x) {
        uint bin = sbin[i];
        uint2 rec = sbuf[i];
        uint slot = gbase[bin] + ((uint)i - sc[bin]);
        if (slot < (uint)BCAP) {
            binbuf[(size_t)bin * BCAP + slot] = rec;
        } else {
            atomicOr(&gcount[bin * GC_STRIDE + 1], 1u);
            spill_rec(rec, bin, gate16h, mid);
        }
    }
}

// ---------------- Pass 2: in-LDS counting sort by edge + register accumulate ----------------
// Block = half a p1 bin (512 edges). Histogram (1 atomic/rec) -> scan -> scatter
// (1 atomic + 1 write/rec) -> thread-per-edge register accumulation (0 atomics)
// -> fc/spill merge -> GatedMLP epilogue. Fallback mode B for fat half-bins.
__global__ void __launch_bounds__(P2_THREADS) p2_sorted_kernel(
        const float* __restrict__ dist,
        const uint* __restrict__ gate16h, // [N,8]
        const uint* __restrict__ gcount,  // [NBIN*GC_STRIDE]
        const uint2* __restrict__ binbuf,
        const float* __restrict__ mid,    // [E,9] spill acc
        const float* __restrict__ attr,
        const float* __restrict__ Wm,
        const float* __restrict__ bm,
        const float* __restrict__ Wg,
        const float* __restrict__ bg,
        float* __restrict__ out,
        int E, int BCAP) {
    __shared__ uint2 srec[SCAP];          // 40 KB; aliased as umid after use
    __shared__ uint cnt[HEPB];
    __shared__ uint off[HEPB];
    __shared__ float sWm[576], sWg[576], sbm[64], sbg[64];
    float* umid = (float*)srec;           // [HEPB*9] aliased

    int tid = threadIdx.x;
    for (int i = tid; i < 576; i += P2_THREADS) { sWm[i] = Wm[i]; sWg[i] = Wg[i]; }
    if (tid < 64) { sbm[tid] = bm[tid]; sbg[tid] = bg[tid]; }
    cnt[tid] = 0;

    int bin = blockIdx.x >> 1;
    int hh  = blockIdx.x & 1;
    int ebase = (bin << EPB_SHIFT) + hh * HEPB;
    int ecnt = E - ebase; if (ecnt < 0) ecnt = 0; if (ecnt > HEPB) ecnt = HEPB;

    uint n = gcount[bin * GC_STRIDE];
    uint has_spill = gcount[bin * GC_STRIDE + 1];
    if (n > (uint)BCAP) n = (uint)BCAP;
    const uint2* rb = binbuf + (size_t)bin * BCAP;
    __syncthreads();

    // pass A: histogram of this half's records
    for (uint i = tid; i < n; i += P2_THREADS) {
        uint ijl = rb[i].y >> 16;
        if ((ijl >> 9) == (uint)hh) atomicAdd(&cnt[ijl & (HEPB - 1u)], 1u);
    }
    __syncthreads();
    uint myCnt = cnt[tid];
    off[tid] = myCnt;
    __syncthreads();
    for (int o = 1; o < HEPB; o <<= 1) {
        uint add = (tid >= o) ? off[tid - o] : 0u;
        __syncthreads();
        off[tid] += add;
        __syncthreads();
    }
    uint total = off[HEPB - 1];
    uint myBase = off[tid] - myCnt;
    __syncthreads();
    off[tid] = myBase;     // exclusive base per edge
    cnt[tid] = 0;          // scatter cursor
    __syncthreads();

    float acc[9];
#pragma unroll
    for (int d = 0; d < 9; ++d) acc[d] = 0.0f;

    if (total <= (uint)SCAP) {
        // mode A: scatter into sorted LDS
        for (uint i = tid; i < n; i += P2_THREADS) {
            uint2 r = rb[i];
            uint ijl = r.y >> 16;
            if ((ijl >> 9) == (uint)hh) {
                uint e = ijl & (HEPB - 1u);
                uint p = off[e] + atomicAdd(&cnt[e], 1u);
                srec[p] = r;
            }
        }
        __syncthreads();
        // thread = edge: serial register accumulation, zero atomics
        for (uint j = 0; j < myCnt; ++j) {
            float c[9];
            contrib9(srec[myBase + j], gate16h, c);
#pragma unroll
            for (int d = 0; d < 9; ++d) acc[d] += c[d];
        }
        __syncthreads();   // all srec reads done before umid aliasing writes
    } else {
        // mode B (rare fat half-bin): atomic accumulate into umid region
        for (int i = tid; i < HEPB * 9; i += P2_THREADS) umid[i] = 0.0f;
        __syncthreads();
        for (uint i = tid; i < n; i += P2_THREADS) {
            uint2 r = rb[i];
            uint ijl = r.y >> 16;
            if ((ijl >> 9) == (uint)hh) {
                uint e = ijl & (HEPB - 1u);
                float c[9];
                contrib9(r, gate16h, c);
                float* d0 = &umid[e * 9];
#pragma unroll
                for (int d = 0; d < 9; ++d) atomicAdd(d0 + d, c[d]);
            }
        }
        __syncthreads();
        if (tid < ecnt) {
#pragma unroll
            for (int d = 0; d < 9; ++d) acc[d] = umid[tid * 9 + d];
        }
        __syncthreads();
    }

    // merge fc(rij) (+ spill) and stage umid for the epilogue
    if (tid < ecnt) {
        int e = ebase + tid;
        float fc = fcut(dist[e]);
        if (has_spill) {
            const float* mg = mid + (size_t)e * 9;
#pragma unroll
            for (int d = 0; d < 9; ++d) acc[d] = fc * (acc[d] + mg[d]);
        } else {
#pragma unroll
            for (int d = 0; d < 9; ++d) acc[d] *= fc;
        }
#pragma unroll
        for (int d = 0; d < 9; ++d) umid[tid * 9 + d] = acc[d];
    }
    __syncthreads();

    // GatedMLP epilogue: wave per edge, lane = feature
    int wid  = tid >> 6;
    int lane = tid & 63;
    for (int el = wid; el < ecnt; el += (P2_THREADS >> 6)) {
        int e = ebase + el;
        const float* ls = &umid[el * 9];
        float am = sbm[lane], ag = sbg[lane];
#pragma unroll
        for (int d = 0; d < 9; ++d) {
            float ud = ls[d];
            am += ud * sWm[d * 64 + lane];
            ag += ud * sWg[d * 64 + lane];
        }
        float hsw = am / (1.0f + __expf(-am));
        float gt  = 1.0f / (1.0f + __expf(-ag));
        size_t ofs = (size_t)e * 64 + lane;
        out[ofs] = attr[ofs] + hsw * gt;
    }
}

// ---------------- Legacy fallback (round-1 path) ----------------
__global__ void triplet_kernel(const float* __restrict__ dist,
                               const float* __restrict__ ang,
                               const int* __restrict__ tidx,
                               const int* __restrict__ eidx,
                               const float* __restrict__ gate,
                               float* __restrict__ mid,
                               int T, int E) {
    int t = blockIdx.x * blockDim.x + threadIdx.x;
    if (t >= T) return;
    int ij = tidx[t];
    int ik = tidx[T + t];
    float ca  = ang[t];
    float rij = dist[ij];
    float rik = dist[ik];
    float frij = fcut(rij);
    int nk = eidx[E + ik];
    const float* g = gate + (size_t)nk * 9;
    float vr[9];
    radial9(rik, vr);
    float s0, s1, s2;
    legendre_s(ca, s0, s1, s2);
    s0 *= frij; s1 *= frij; s2 *= frij;
    float* dst = mid + (size_t)ij * 9;
    atomicAdd(dst + 0, vr[0] * s0 * g[0]);
    atomicAdd(dst + 1, vr[1] * s0 * g[1]);
    atomicAdd(dst + 2, vr[2] * s0 * g[2]);
    atomicAdd(dst + 3, vr[3] * s1 * g[3]);
    atomicAdd(dst + 4, vr[4] * s1 * g[4]);
    atomicAdd(dst + 5, vr[5] * s1 * g[5]);
    atomicAdd(dst + 6, vr[6] * s2 * g[6]);
    atomicAdd(dst + 7, vr[7] * s2 * g[7]);
    atomicAdd(dst + 8, vr[8] * s2 * g[8]);
}

__global__ void edge_kernel(const float* __restrict__ mid,
                            const float* __restrict__ attr,
                            const float* __restrict__ Wm, const float* __restrict__ bm,
                            const float* __restrict__ Wg, const float* __restrict__ bg,
                            float* __restrict__ out, int E) {
    __shared__ float sWm[9 * 64], sWg[9 * 64], sbm[64], sbg[64];
    for (int i = threadIdx.x; i < 576; i += blockDim.x) {
        sWm[i] = Wm[i];
        sWg[i] = Wg[i];
    }
    if (threadIdx.x < 64) {
        sbm[threadIdx.x] = bm[threadIdx.x];
        sbg[threadIdx.x] = bg[threadIdx.x];
    }
    __syncthreads();
    int wid  = threadIdx.x >> 6;
    int lane = threadIdx.x & 63;
    int e = blockIdx.x * (blockDim.x >> 6) + wid;
    if (e >= E) return;
    const float* u = mid + (size_t)e * 9;
    float am = sbm[lane], ag = sbg[lane];
#pragma unroll
    for (int d = 0; d < 9; ++d) {
        float ud = u[d];
        am += ud * sWm[d * 64 + lane];
        ag += ud * sWg[d * 64 + lane];
    }
    float h  = am / (1.0f + __expf(-am));
    float gt = 1.0f / (1.0f + __expf(-ag));
    size_t off = (size_t)e * 64 + lane;
    out[off] = attr[off] + h * gt;
}

extern "C" void kernel_launch(void* const* d_in, const int* in_sizes, int n_in,
                              void* d_out, int out_size, void* d_ws, size_t ws_size,
                              hipStream_t stream) {
    const float* dist = (const float*)d_in[0];
    const float* ang  = (const float*)d_in[1];
    const float* nf   = (const float*)d_in[2];
    const float* attr = (const float*)d_in[3];
    const float* W1   = (const float*)d_in[4];
    const float* b1   = (const float*)d_in[5];
    const float* Wm   = (const float*)d_in[6];
    const float* bm   = (const float*)d_in[7];
    const float* Wg   = (const float*)d_in[8];
    const float* bg   = (const float*)d_in[9];
    const int* tidx   = (const int*)d_in[10];
    const int* eidx   = (const int*)d_in[11];

    int E = in_sizes[0];
    int T = in_sizes[1];
    int N = in_sizes[2] / 64;

    int NBIN = (E + EPB - 1) >> EPB_SHIFT;
    int mean = T / (NBIN > 0 ? NBIN : 1);

    int bcap1 = ((mean + mean / 8 + 512) + 15) & ~15;
    int bcap2 = ((mean + mean / 32 + 256) + 15) & ~15;

    size_t o_gate  = 0;
    size_t o_tab   = o_gate + (size_t)N * 8;
    size_t o_mid   = o_tab + (size_t)E;
    size_t o_gcnt  = o_mid + (size_t)E * 9;
    size_t o_bb    = (o_gcnt + (size_t)NBIN * GC_STRIDE + 15) & ~(size_t)15;
    auto need = [&](int cap) { return (o_bb + (size_t)NBIN * cap * 2) * 4; };

    int BCAP = 0;
    if (ws_size >= need(bcap1)) BCAP = bcap1;
    else if (ws_size >= need(bcap2)) BCAP = bcap2;

    bool newpath = (E <= (1 << 20)) && (N <= 65535) && (NBIN <= NBIN_MAX)
                   && (NBIN <= P1_THREADS) && (BCAP > 0);

    float* wsf = (float*)d_ws;

    if (newpath) {
        uint*  gate16h = (uint*)(wsf + o_gate);
        uint*  tab     = (uint*)(wsf + o_tab);
        float* mid     = wsf + o_mid;
        uint*  gcount  = (uint*)(wsf + o_gcnt);
        uint2* binbuf  = (uint2*)(wsf + o_bb);

        hipMemsetAsync(gcount, 0, (size_t)NBIN * GC_STRIDE * sizeof(uint), stream);
        hipMemsetAsync(mid, 0, (size_t)E * 9 * sizeof(float), stream);
        node_gate_h16_kernel<<<(N + 255) / 256, 256, 0, stream>>>(nf, W1, b1, gate16h, N);
        edge_tab_kernel<<<(E + 255) / 256, 256, 0, stream>>>(dist, eidx, tab, E);

        int p1grid = (T + P1_CHUNK - 1) / P1_CHUNK;
        p1_sort_kernel<<<p1grid, P1_THREADS, 0, stream>>>(ang, tidx, tab, gcount, binbuf,
                                                          gate16h, mid, T, NBIN, BCAP);
        p2_sorted_kernel<<<NBIN * 2, P2_THREADS, 0, stream>>>(dist, gate16h, gcount, binbuf, mid,
                                                              attr, Wm, bm, Wg, bg,
                                                              (float*)d_out, E, BCAP);
    } else {
        float* gate = wsf;
        float* mid = gate + (((size_t)N * 9 + 15) & ~(size_t)15);
        hipMemsetAsync(mid, 0, (size_t)E * 9 * sizeof(float), stream);
        node_gate_f32_kernel<<<(N + 255) / 256, 256, 0, stream>>>(nf, W1, b1, gate, N);
        triplet_kernel<<<(T + 255) / 256, 256, 0, stream>>>(dist, ang, tidx, eidx, gate, mid, T, E);
        edge_kernel<<<(E + 3) / 4, 256, 0, stream>>>(mid, attr, Wm, bm, Wg, bg, (float*)d_out, E);
    }
}